// Round 4
// baseline (169.984 us; speedup 1.0000x reference)
//
#include <hip/hip_runtime.h>

// ---------- kernel 1: bucket tokens by partition ----------
// Two-phase block-aggregated atomics (R2 fix: 64us same-line serialization -> ~3us).
__global__ void bucket_k(const int* __restrict__ x, const int* __restrict__ parts,
                         int* __restrict__ counts, int* __restrict__ buckets, int NT) {
    __shared__ int lcount[8];
    __shared__ int lbase[8];
    const int tid = threadIdx.x;
    if (tid < 8) lcount[tid] = 0;
    __syncthreads();

    const int i = blockIdx.x * blockDim.x + tid;
    int p = 0, lpos = 0;
    const bool valid = (i < NT);
    if (valid) {
        p = parts[x[i]];
        lpos = atomicAdd(&lcount[p], 1);
    }
    __syncthreads();
    if (tid < 8)
        lbase[tid] = lcount[tid] ? atomicAdd(&counts[tid], lcount[tid]) : 0;
    __syncthreads();
    if (valid)
        buckets[(size_t)p * NT + lbase[p] + lpos] = i;
}

// ---------- kernel 2: grouped GEMM per partition (fp32) ----------
// R3 restructure: block = 32 tokens x ALL 256 z. E gathered from HBM ONCE per
// token (was x4 in R2); W streamed per-chunk from L2 (2 MB table, L2-resident).
// LDS 36.6 KB -> 4 blocks/CU (was 72.7 KB -> 2). Per lane: 4 tok x 8 z accs;
// inner step = 3 conflict-free ds_read_b128 + 32 FMA (FMA-bound).
#define TT 32     // tokens per tile
#define KC 32     // K chunk
#define XB 80     // tiles per partition per sweep (covers n_p <= 2560)

__global__ __launch_bounds__(256)
void fge_gemm(const int* __restrict__ x,
              const float* __restrict__ emb,
              const float* __restrict__ weight,
              const int* __restrict__ counts,
              const int* __restrict__ buckets,
              float* __restrict__ out, int NT) {
    const int p = blockIdx.y;
    const int n = counts[p];
    if ((int)(blockIdx.x * TT) >= n) return;        // block-uniform early exit
    const int K   = 256 >> p;                       // active input dim
    const int nch = (K + KC - 1) / KC;
    const int tid = threadIdx.x;

    __shared__ __align__(16) float e_lds[KC][TT];   // [x][tok]  4 KB
    __shared__ __align__(16) float w_lds[KC][256];  // [x][z]   32 KB
    __shared__ int vrow[TT];
    __shared__ int oidx[TT];

    const int tt  = tid & 7;      // token group: owns tokens tt*4 .. +3
    const int tz  = tid >> 3;     // z group:     owns z = tz*8 .. +7
    const int t_s = tid & 31;     // E staging: token slot
    const int xh  = tid >> 5;     // E staging: x sub-range xh*4 .. +3

    for (int t0 = blockIdx.x * TT; t0 < n; t0 += XB * TT) {
        const int ntile = min(TT, n - t0);

        __syncthreads();          // protect prior iter's LDS / vrow
        if (tid < TT) {
            int idx = 0, row = 0;
            if (tid < ntile) {
                idx = buckets[(size_t)p * NT + t0 + tid];
                row = x[idx];
            }
            oidx[tid] = idx;
            vrow[tid] = row;      // row 0 for invalid slots: safe dummy reads
        }
        __syncthreads();

        float acc[4][8] = {};

        for (int ch = 0; ch < nch; ++ch) {
            // ---- stage E chunk [KC][TT] (zero beyond K / beyond ntile) ----
            {
                const bool tv = (t_s < ntile);
                const int gxb = ch * KC + xh * 4;
                const float4 v = *(const float4*)(emb + (size_t)vrow[t_s] * 256 + gxb);
                const float va[4] = {v.x, v.y, v.z, v.w};
#pragma unroll
                for (int c = 0; c < 4; ++c)
                    e_lds[xh * 4 + c][t_s] = (tv && (gxb + c) < K) ? va[c] : 0.f;
            }
            // ---- stage W chunk [KC][256] from L2 (z row = tid) ----
            {
                const float* wr = weight + ((size_t)p * 256 + tid) * 256 + ch * KC;
#pragma unroll
                for (int i = 0; i < KC / 4; ++i) {
                    const float4 v = *(const float4*)(wr + i * 4);
                    w_lds[i * 4 + 0][tid] = v.x;
                    w_lds[i * 4 + 1][tid] = v.y;
                    w_lds[i * 4 + 2][tid] = v.z;
                    w_lds[i * 4 + 3][tid] = v.w;
                }
            }
            __syncthreads();

            // ---- compute: KC x-steps, 3 ds_read_b128 + 32 FMA each ----
#pragma unroll
            for (int c = 0; c < KC; ++c) {
                const float4 ev = *(const float4*)&e_lds[c][tt * 4];
                const float4 w0 = *(const float4*)&w_lds[c][tz * 8];
                const float4 w1 = *(const float4*)&w_lds[c][tz * 8 + 4];
                const float ea[4] = {ev.x, ev.y, ev.z, ev.w};
                const float wa[8] = {w0.x, w0.y, w0.z, w0.w, w1.x, w1.y, w1.z, w1.w};
#pragma unroll
                for (int i = 0; i < 4; ++i)
#pragma unroll
                    for (int j = 0; j < 8; ++j)
                        acc[i][j] = fmaf(ea[i], wa[j], acc[i][j]);
            }
            __syncthreads();      // before next chunk overwrites e/w
        }

        // ---- epilogue: 2x float4 per (lane, token) ----
#pragma unroll
        for (int i = 0; i < 4; ++i) {
            const int t = tt * 4 + i;
            if (t < ntile) {
                float* op = out + (size_t)oidx[t] * 256 + tz * 8;
                float4 o0 = {acc[i][0], acc[i][1], acc[i][2], acc[i][3]};
                float4 o1 = {acc[i][4], acc[i][5], acc[i][6], acc[i][7]};
                *(float4*)op = o0;
                *(float4*)(op + 4) = o1;
            }
        }
    }
}

// ---------- generic fallback (any D/P, or ws too small) ----------
__global__ void naive_k(const int* __restrict__ x, const float* __restrict__ emb,
                        const float* __restrict__ w, const int* __restrict__ parts,
                        float* __restrict__ out, int D, int P) {
    const int i = blockIdx.x;
    const int tokrow = x[i];
    const int p = parts[tokrow];
    const int K = D >> p;
    const float* er = emb + (size_t)tokrow * D;
    for (int z = threadIdx.x; z < D; z += blockDim.x) {
        const float* wr = w + ((size_t)p * D + z) * D;
        float acc = 0.f;
        for (int k = 0; k < K; ++k) acc = fmaf(er[k], wr[k], acc);
        out[(size_t)i * D + z] = acc;
    }
}

extern "C" void kernel_launch(void* const* d_in, const int* in_sizes, int n_in,
                              void* d_out, int out_size, void* d_ws, size_t ws_size,
                              hipStream_t stream) {
    const int*   xi    = (const int*)d_in[0];
    const float* emb   = (const float*)d_in[1];
    const float* wgt   = (const float*)d_in[2];
    const int*   parts = (const int*)d_in[3];
    float* out = (float*)d_out;

    const int NT = in_sizes[0];
    const long long V = in_sizes[3];
    const int D = (int)(in_sizes[1] / V);
    const int P = (int)(in_sizes[2] / ((long long)D * D));
    const size_t need = 32 + (size_t)P * (size_t)NT * sizeof(int);

    if (D == 256 && P == 8 && ws_size >= need) {
        int* counts  = (int*)d_ws;
        int* buckets = (int*)((char*)d_ws + 32);
        hipMemsetAsync(counts, 0, 32, stream);
        bucket_k<<<(NT + 255) / 256, 256, 0, stream>>>(xi, parts, counts, buckets, NT);
        dim3 grid(XB, 8);
        fge_gemm<<<grid, 256, 0, stream>>>(xi, emb, wgt, counts, buckets, out, NT);
    } else {
        naive_k<<<NT, 256, 0, stream>>>(xi, emb, wgt, parts, out, D, P);
    }
}

// Round 5
// 167.960 us; speedup vs baseline: 1.0120x; 1.0120x over previous
//
#include <hip/hip_runtime.h>

// ---------- kernel 1: bucket tokens by partition ----------
__global__ void bucket_k(const int* __restrict__ x, const int* __restrict__ parts,
                         int* __restrict__ counts, int* __restrict__ buckets, int NT) {
    __shared__ int lcount[8];
    __shared__ int lbase[8];
    const int tid = threadIdx.x;
    if (tid < 8) lcount[tid] = 0;
    __syncthreads();

    const int i = blockIdx.x * blockDim.x + tid;
    int p = 0, lpos = 0;
    const bool valid = (i < NT);
    if (valid) {
        p = parts[x[i]];
        lpos = atomicAdd(&lcount[p], 1);
    }
    __syncthreads();
    if (tid < 8)
        lbase[tid] = lcount[tid] ? atomicAdd(&counts[tid], lcount[tid]) : 0;
    __syncthreads();
    if (valid)
        buckets[(size_t)p * NT + lbase[p] + lpos] = i;
}

// ---------- kernel 2: grouped GEMM per partition (fp32) ----------
// R4: all-coalesced staging + swizzled W transpose + 4 blocks/CU.
//  - E staged row-major [t][k]: global float4 reads are 256B-contiguous per row,
//    LDS writes are b128 conflict-free. No per-element transpose scatter.
//  - W staged [k][z] swizzled (z' = (z+4k)&63): global reads 64B-coalesced,
//    write conflicts capped at 8-way (staging only), compute reads 2-way (free).
//  - Inner 4k-step: 8 ds_read_b128 per 64 FMA, acc[4 tok][4 z] per lane.
//  - LDS 32.5 KB -> 4 blocks/CU, 16 waves: chunk barriers overlap across blocks.
#define TT 64     // tokens per tile
#define XB 40     // token-tile grid (covers n_p <= 2560; loop beyond)

__global__ __launch_bounds__(256)
void fge_gemm(const int* __restrict__ x,
              const float* __restrict__ emb,
              const float* __restrict__ weight,
              const int* __restrict__ counts,
              const int* __restrict__ buckets,
              float* __restrict__ out, int NT) {
    const int p = blockIdx.z;
    const int n = counts[p];
    if ((int)(blockIdx.x * TT) >= n) return;
    const int z0  = blockIdx.y * 64;
    const int K   = 256 >> p;                 // true active dim
    const int KP  = (K < 16) ? 16 : K;        // zero-padded K (keeps b128 strides)
    const int KC  = (KP < 64) ? KP : 64;      // K chunk size (16/32/64)
    const int nch = KP / KC;
    const int tid = threadIdx.x;

    __shared__ __align__(16) float e_lds[TT * 64];   // [t][k], row stride KC, 16 KB max
    __shared__ __align__(16) float w_lds[64 * 64];   // [k][z] swizzled, 16 KB max
    __shared__ int vrow[TT];
    __shared__ int oidx[TT];

    const int tg  = tid >> 4;        // token group: owns tokens tg*4 .. +3
    const int zg4 = (tid & 15) * 4;  // z offset: owns z0+zg4 .. +3

    for (int t0 = blockIdx.x * TT; t0 < n; t0 += XB * TT) {
        const int ntile = min(TT, n - t0);

        __syncthreads();             // protect prior iter's LDS
        if (tid < TT) {
            int idx = 0, row = 0;
            if (tid < ntile) {
                idx = buckets[(size_t)p * NT + t0 + tid];
                row = x[idx];
            }
            oidx[tid] = idx;
            vrow[tid] = row;         // row 0 for invalid slots: safe dummy loads
        }
        __syncthreads();

        float acc[4][4] = {};

        for (int ch = 0; ch < nch; ++ch) {
            const int kbase = ch * KC;
            const int lpr   = KC >> 2;               // float4 lanes per row

            // ---- stage E [TT][KC] row-major, coalesced ----
            {
                const int passes = (TT * lpr) >> 8;  // KC=64:4, 32:2, 16:1
                for (int ps = 0; ps < passes; ++ps) {
                    const int idx = ps * 256 + tid;
                    const int row = idx / lpr;
                    const int c4  = (idx - row * lpr) * 4;
                    const float4 v = *(const float4*)(emb + (size_t)vrow[row] * 256 + kbase + c4);
                    float4 o;
                    o.x = (kbase + c4 + 0 < K) ? v.x : 0.f;
                    o.y = (kbase + c4 + 1 < K) ? v.y : 0.f;
                    o.z = (kbase + c4 + 2 < K) ? v.z : 0.f;
                    o.w = (kbase + c4 + 3 < K) ? v.w : 0.f;
                    *(float4*)&e_lds[row * KC + c4] = o;
                }
            }
            // ---- stage W [KC][64] transposed + swizzled, coalesced reads ----
            {
                const int passes = (64 * lpr) >> 8;  // KC=64:4, 32:2, 16:1
                for (int ps = 0; ps < passes; ++ps) {
                    const int idx = ps * 256 + tid;
                    const int rz  = idx / lpr;
                    const int c4  = (idx - rz * lpr) * 4;
                    const float4 v = *(const float4*)(weight + ((size_t)p * 256 + z0 + rz) * 256 + kbase + c4);
                    const float vv[4] = {v.x, v.y, v.z, v.w};
#pragma unroll
                    for (int j = 0; j < 4; ++j) {
                        const int kk = c4 + j;
                        w_lds[kk * 64 + ((rz + 4 * kk) & 63)] =
                            (kbase + kk < K) ? vv[j] : 0.f;
                    }
                }
            }
            __syncthreads();

            // ---- compute: KC/4 macro-steps, 8 ds_read_b128 + 64 FMA each ----
            const float* e0 = &e_lds[(tg * 4 + 0) * KC];
            const float* e1 = &e_lds[(tg * 4 + 1) * KC];
            const float* e2 = &e_lds[(tg * 4 + 2) * KC];
            const float* e3 = &e_lds[(tg * 4 + 3) * KC];
#pragma unroll 2
            for (int k = 0; k < KC; k += 4) {
                const float4 a0 = *(const float4*)(e0 + k);
                const float4 a1 = *(const float4*)(e1 + k);
                const float4 a2 = *(const float4*)(e2 + k);
                const float4 a3 = *(const float4*)(e3 + k);
                float4 w[4];
#pragma unroll
                for (int j = 0; j < 4; ++j)
                    w[j] = *(const float4*)&w_lds[(k + j) * 64 + ((zg4 + 4 * (k + j)) & 63)];
                const float ea[4][4] = {{a0.x,a0.y,a0.z,a0.w}, {a1.x,a1.y,a1.z,a1.w},
                                        {a2.x,a2.y,a2.z,a2.w}, {a3.x,a3.y,a3.z,a3.w}};
                const float wv[4][4] = {{w[0].x,w[0].y,w[0].z,w[0].w}, {w[1].x,w[1].y,w[1].z,w[1].w},
                                        {w[2].x,w[2].y,w[2].z,w[2].w}, {w[3].x,w[3].y,w[3].z,w[3].w}};
#pragma unroll
                for (int i = 0; i < 4; ++i)
#pragma unroll
                    for (int j = 0; j < 4; ++j) {
                        acc[i][0] = fmaf(ea[i][j], wv[j][0], acc[i][0]);
                        acc[i][1] = fmaf(ea[i][j], wv[j][1], acc[i][1]);
                        acc[i][2] = fmaf(ea[i][j], wv[j][2], acc[i][2]);
                        acc[i][3] = fmaf(ea[i][j], wv[j][3], acc[i][3]);
                    }
            }
            __syncthreads();         // before next chunk overwrites e/w
        }

        // ---- epilogue: float4 per (token, lane); 256B-contiguous per token ----
#pragma unroll
        for (int i = 0; i < 4; ++i) {
            const int t = tg * 4 + i;
            if (t < ntile) {
                float4 o = {acc[i][0], acc[i][1], acc[i][2], acc[i][3]};
                *(float4*)(out + (size_t)oidx[t] * 256 + z0 + zg4) = o;
            }
        }
    }
}

// ---------- generic fallback (any D/P, or ws too small) ----------
__global__ void naive_k(const int* __restrict__ x, const float* __restrict__ emb,
                        const float* __restrict__ w, const int* __restrict__ parts,
                        float* __restrict__ out, int D, int P) {
    const int i = blockIdx.x;
    const int tokrow = x[i];
    const int p = parts[tokrow];
    const int K = D >> p;
    const float* er = emb + (size_t)tokrow * D;
    for (int z = threadIdx.x; z < D; z += blockDim.x) {
        const float* wr = w + ((size_t)p * D + z) * D;
        float acc = 0.f;
        for (int k = 0; k < K; ++k) acc = fmaf(er[k], wr[k], acc);
        out[(size_t)i * D + z] = acc;
    }
}

extern "C" void kernel_launch(void* const* d_in, const int* in_sizes, int n_in,
                              void* d_out, int out_size, void* d_ws, size_t ws_size,
                              hipStream_t stream) {
    const int*   xi    = (const int*)d_in[0];
    const float* emb   = (const float*)d_in[1];
    const float* wgt   = (const float*)d_in[2];
    const int*   parts = (const int*)d_in[3];
    float* out = (float*)d_out;

    const int NT = in_sizes[0];
    const long long V = in_sizes[3];
    const int D = (int)(in_sizes[1] / V);
    const int P = (int)(in_sizes[2] / ((long long)D * D));
    const size_t need = 32 + (size_t)P * (size_t)NT * sizeof(int);

    if (D == 256 && P == 8 && ws_size >= need) {
        int* counts  = (int*)d_ws;
        int* buckets = (int*)((char*)d_ws + 32);
        hipMemsetAsync(counts, 0, 32, stream);
        bucket_k<<<(NT + 255) / 256, 256, 0, stream>>>(xi, parts, counts, buckets, NT);
        dim3 grid(XB, 4, 8);
        fge_gemm<<<grid, 256, 0, stream>>>(xi, emb, wgt, counts, buckets, out, NT);
    } else {
        naive_k<<<NT, 256, 0, stream>>>(xi, emb, wgt, parts, out, D, P);
    }
}